// Round 1
// baseline (75.835 us; speedup 1.0000x reference)
//
#include <hip/hip_runtime.h>
#include <hip/hip_bf16.h>
#include <math.h>

// Problem constants (from reference): B=8, L=256, H=128, all fp32.
#define NB 8
#define NL 256
#define NH 128

using bf16   = __bf16;
using bf16x8 = __attribute__((ext_vector_type(8))) __bf16;
using bf16x4 = __attribute__((ext_vector_type(4))) __bf16;
using f32x4  = __attribute__((ext_vector_type(4))) float;

// ---------------------------------------------------------------------------
// Prep kernel: blocks 0..7  -> agg[b,h] = sum_l wmask[b,l]*wei[b,l,h]
//              blocks 8..15 -> doc_bf = bf16(doc)
//              block  16    -> wpk: W1a packed in MFMA B-fragment order, bf16
// Fragment k-bijection f(g,j) = 8*g + j (g = lane>>4, j = slot 0..7) is used
// identically for A and B, so correctness is independent of the HW k-map.
// ---------------------------------------------------------------------------
__global__ __launch_bounds__(256) void prep_kernel(
    const float* __restrict__ wei, const float* __restrict__ wmask,
    const float* __restrict__ doc, const float* __restrict__ W1,
    bf16* __restrict__ doc_bf, bf16* __restrict__ wpk, float* __restrict__ agg)
{
    int blk = blockIdx.x;
    int t   = threadIdx.x;
    if (blk < NB) {
        __shared__ float part[8][NH];
        int b  = blk;
        int hq = t & 31;   // float4 column
        int lg = t >> 5;   // 0..7 row-group
        f32x4 acc = {0.f, 0.f, 0.f, 0.f};
        for (int s = 0; s < 32; ++s) {
            int l = lg * 32 + s;
            float m = wmask[b * NL + l];
            f32x4 v = *reinterpret_cast<const f32x4*>(&wei[(b * NL + l) * NH + hq * 4]);
            acc += m * v;
        }
        *reinterpret_cast<f32x4*>(&part[lg][hq * 4]) = acc;
        __syncthreads();
        if (t < NH) {
            float s = 0.f;
            #pragma unroll
            for (int g = 0; g < 8; ++g) s += part[g][t];
            agg[b * NH + t] = s;
        }
    } else if (blk < 16) {
        int b = blk - 8;
        const float* src = doc + b * NL * NH;
        bf16* dst = doc_bf + (size_t)b * NL * NH;
        for (int c = 0; c < 32; ++c) {
            int idx = c * 1024 + t * 4;
            f32x4 v = *reinterpret_cast<const f32x4*>(&src[idx]);
            bf16x4 o = { (bf16)v.x, (bf16)v.y, (bf16)v.z, (bf16)v.w };
            *reinterpret_cast<bf16x4*>(&dst[idx]) = o;
        }
    } else {
        // Pack W1a (= W1[0:128,:]) into fragment order:
        // wpk[((kk*8+nt)*64 + lane)*8 + j] = W1[(kk*32 + (lane>>4)*8 + j)*128 + nt*16 + (lane&15)]
        for (int c = 0; c < 64; ++c) {
            int o  = c * 256 + t;
            int j  = o & 7;
            int l  = (o >> 3) & 63;
            int nt = (o >> 9) & 7;
            int kk = (o >> 12) & 3;
            int h   = kk * 32 + (l >> 4) * 8 + j;
            int col = nt * 16 + (l & 15);
            wpk[o] = (bf16)W1[h * NH + col];
        }
    }
}

// ---------------------------------------------------------------------------
// Main kernel: one block per (b,i). 256 threads = 4 waves.
//  A[j][h] = bf16(doc_bf[b,j,h] * doc[b,i,h]) staged in LDS (pad +8 bf16).
//  pre = A @ W1a via mfma_f32_16x16x32_bf16, +term_i, tanh, dot W2 -> score[j]
//  softmax over j, then out[b,i,:] = w @ doc[b,:,:]
// ---------------------------------------------------------------------------
__global__ __launch_bounds__(256, 2) void main_kernel(
    const float* __restrict__ doc, const float* __restrict__ dmask,
    const float* __restrict__ W1, const float* __restrict__ b1,
    const float* __restrict__ W2, const float* __restrict__ b2p,
    const bf16* __restrict__ doc_bf, const bf16* __restrict__ wpk,
    const float* __restrict__ agg, float* __restrict__ out)
{
    __shared__ bf16  Alds[NL][NH + 8];   // 69632 B, pad keeps 16B align, 2-way banks
    __shared__ float dif[NH];            // doc[b,i,:] fp32
    __shared__ float term2[2][NH];
    __shared__ float termf[NH];
    __shared__ float w2s[NH];
    __shared__ float dmr[NL];
    __shared__ float score[NL];
    __shared__ float red[8];

    int bid = blockIdx.x;
    int b = bid >> 8;
    int i = bid & 255;
    int t = threadIdx.x;

    const float* di_row = doc + (b * NL + i) * NH;

    // ---- Phase A0: stage small vectors ----
    if (t < NH) {
        dif[t] = di_row[t];
        w2s[t] = W2[t];
    }
    dmr[t] = dmask[b * NL + t];
    __syncthreads();

    // ---- Phase A1: term partials + A build ----
    {
        int k  = t & 127;
        int hh = t >> 7;
        float s = 0.f;
        const float* aggb = agg + b * NH;
        for (int h = hh * 64; h < hh * 64 + 64; ++h) {
            float wea = dif[h] * aggb[h];
            s = fmaf(wea, W1[(NH + h) * NH + k], s);
        }
        term2[hh][k] = s;
    }
    {
        const bf16* drow = doc_bf + ((size_t)b * NL + t) * NH;
        #pragma unroll
        for (int c = 0; c < 16; ++c) {
            bf16x8 v = *reinterpret_cast<const bf16x8*>(&drow[c * 8]);
            f32x4 d0 = *reinterpret_cast<const f32x4*>(&dif[c * 8]);
            f32x4 d1 = *reinterpret_cast<const f32x4*>(&dif[c * 8 + 4]);
            bf16x8 a;
            a[0] = (bf16)((float)v[0] * d0.x);
            a[1] = (bf16)((float)v[1] * d0.y);
            a[2] = (bf16)((float)v[2] * d0.z);
            a[3] = (bf16)((float)v[3] * d0.w);
            a[4] = (bf16)((float)v[4] * d1.x);
            a[5] = (bf16)((float)v[5] * d1.y);
            a[6] = (bf16)((float)v[6] * d1.z);
            a[7] = (bf16)((float)v[7] * d1.w);
            *reinterpret_cast<bf16x8*>(&Alds[t][c * 8]) = a;
        }
    }
    __syncthreads();
    if (t < NH) termf[t] = term2[0][t] + term2[1][t] + b1[t];
    __syncthreads();

    // ---- Phase B: GEMM  pre[j,k] = A[j,:] @ W1a[:,k] ----
    int wv  = t >> 6;
    int ln  = t & 63;
    int l15 = ln & 15;
    int g   = ln >> 4;
    int jbase = wv * 64;

    f32x4 acc[4][8];
    #pragma unroll
    for (int mt = 0; mt < 4; ++mt)
        #pragma unroll
        for (int nt = 0; nt < 8; ++nt)
            acc[mt][nt] = (f32x4){0.f, 0.f, 0.f, 0.f};

    #pragma unroll
    for (int kk = 0; kk < 4; ++kk) {
        bf16x8 bq[8];
        #pragma unroll
        for (int nt = 0; nt < 8; ++nt)
            bq[nt] = *reinterpret_cast<const bf16x8*>(&wpk[(((kk * 8 + nt) * 64) + ln) * 8]);
        #pragma unroll
        for (int mt = 0; mt < 4; ++mt) {
            bf16x8 aq = *reinterpret_cast<const bf16x8*>(
                &Alds[jbase + mt * 16 + l15][kk * 32 + g * 8]);
            #pragma unroll
            for (int nt = 0; nt < 8; ++nt)
                acc[mt][nt] = __builtin_amdgcn_mfma_f32_16x16x32_bf16(
                    aq, bq[nt], acc[mt][nt], 0, 0, 0);
        }
    }

    // ---- Phase C: epilogue  tanh(pre+term) . W2 -> score[j] ----
    float b2v = b2p[0];
    float dmi = dmask[b * NL + i];

    float tf[8], w2v[8];
    #pragma unroll
    for (int nt = 0; nt < 8; ++nt) {
        tf[nt]  = termf[nt * 16 + l15];
        w2v[nt] = w2s[nt * 16 + l15];
    }
    float sp[4][4];
    #pragma unroll
    for (int mt = 0; mt < 4; ++mt)
        #pragma unroll
        for (int r = 0; r < 4; ++r) sp[mt][r] = 0.f;

    #pragma unroll
    for (int mt = 0; mt < 4; ++mt)
        #pragma unroll
        for (int nt = 0; nt < 8; ++nt)
            #pragma unroll
            for (int r = 0; r < 4; ++r) {
                float v  = acc[mt][nt][r] + tf[nt];
                float e  = __expf(2.0f * v);
                float th = 1.0f - 2.0f * __builtin_amdgcn_rcpf(e + 1.0f);
                sp[mt][r] = fmaf(th, w2v[nt], sp[mt][r]);
            }

    #pragma unroll
    for (int mt = 0; mt < 4; ++mt)
        #pragma unroll
        for (int r = 0; r < 4; ++r) {
            float s = sp[mt][r];
            s += __shfl_xor(s, 1);
            s += __shfl_xor(s, 2);
            s += __shfl_xor(s, 4);
            s += __shfl_xor(s, 8);
            if (l15 == 0) {
                int j = jbase + mt * 16 + g * 4 + r;
                float sc = (s + b2v) * 0.08838834764831845f; // 1/sqrt(128)
                float mp = dmr[j] * dmi;
                score[j] = (mp == 0.f) ? -1e9f : sc;
            }
        }
    __syncthreads();

    // ---- Phase D: softmax over j (thread t owns j=t) ----
    float s = score[t];
    float mx = s;
    #pragma unroll
    for (int off = 1; off < 64; off <<= 1) mx = fmaxf(mx, __shfl_xor(mx, off));
    if ((t & 63) == 0) red[wv] = mx;
    __syncthreads();
    mx = fmaxf(fmaxf(red[0], red[1]), fmaxf(red[2], red[3]));
    float e = __expf(s - mx);
    float sm = e;
    #pragma unroll
    for (int off = 1; off < 64; off <<= 1) sm += __shfl_xor(sm, off);
    if ((t & 63) == 0) red[4 + wv] = sm;
    __syncthreads();
    sm = red[4] + red[5] + red[6] + red[7];
    float mp = dmr[t] * dmi;
    float w = e / sm * mp;
    __syncthreads();          // everyone past reading red[] / score[]
    score[t] = w;             // reuse score[] as w[]
    __syncthreads();

    // ---- Phase E: out[b,i,:] = w @ doc[b,:,:]  (Alds reused as scratch) ----
    float* part = reinterpret_cast<float*>(&Alds[0][0]);
    {
        int hq = t & 31;   // float4 column
        int jg = t >> 5;   // 0..7
        f32x4 oa = {0.f, 0.f, 0.f, 0.f};
        const float* docb = doc + b * NL * NH;
        for (int s2 = 0; s2 < 32; ++s2) {
            int j = jg * 32 + s2;
            float wj = score[j];
            f32x4 dv = *reinterpret_cast<const f32x4*>(&docb[j * NH + hq * 4]);
            oa += wj * dv;
        }
        *reinterpret_cast<f32x4*>(&part[(jg * 32 + hq) * 4]) = oa;
    }
    __syncthreads();
    if (t < 32) {
        f32x4 o = {0.f, 0.f, 0.f, 0.f};
        #pragma unroll
        for (int gp = 0; gp < 8; ++gp)
            o += *reinterpret_cast<const f32x4*>(&part[(gp * 32 + t) * 4]);
        *reinterpret_cast<f32x4*>(&out[(b * NL + i) * NH + t * 4]) = o;
    }
}

// ---------------------------------------------------------------------------
extern "C" void kernel_launch(void* const* d_in, const int* in_sizes, int n_in,
                              void* d_out, int out_size, void* d_ws, size_t ws_size,
                              hipStream_t stream) {
    const float* wei   = (const float*)d_in[0];
    const float* wmask = (const float*)d_in[1];
    const float* doc   = (const float*)d_in[2];
    const float* dmask = (const float*)d_in[3];
    const float* W1    = (const float*)d_in[4];
    const float* b1    = (const float*)d_in[5];
    const float* W2    = (const float*)d_in[6];
    const float* b2    = (const float*)d_in[7];
    float* out = (float*)d_out;

    char* ws = (char*)d_ws;
    bf16*  doc_bf = (bf16*)ws;                         // 8*256*128*2 = 524288 B
    bf16*  wpk    = (bf16*)(ws + 524288);              // 16384*2     =  32768 B
    float* agg    = (float*)(ws + 524288 + 32768);     // 8*128*4     =   4096 B

    prep_kernel<<<17, 256, 0, stream>>>(wei, wmask, doc, W1, doc_bf, wpk, agg);
    main_kernel<<<NB * NL, 256, 0, stream>>>(doc, dmask, W1, b1, W2, b2,
                                             doc_bf, wpk, agg, out);
}